// Round 5
// baseline (380.004 us; speedup 1.0000x reference)
//
#include <hip/hip_runtime.h>
#include <hip/hip_bf16.h>
#include <climits>
#include <cstdint>
#include <cfloat>

#define NROWS   524288
#define KDIM    128
#define NGRAPH  64
#define NSTROKE 8192
#define EPSF    1e-5f

typedef __bf16 bf16x8 __attribute__((ext_vector_type(8)));
typedef float  f32x4  __attribute__((ext_vector_type(4)));
typedef unsigned short u16x4 __attribute__((ext_vector_type(4)));

// ws layout (bytes)
#define WT_OFF    0                         // ushort bf16 Wt[256][128] (col-major)
#define CSUM_OFF  65536                     // float[256]
#define CSQ_OFF   66560                     // float[256]
#define ST_OFF    67584                     // int [8192][128] stroke max (int-key)
#define GT_OFF    (ST_OFF + NSTROKE*KDIM*4) // int [64][128] graph max (int-key)

__device__ __forceinline__ unsigned short f2bf(float f) {
  unsigned int u = __float_as_uint(f);
  u += 0x7fffu + ((u >> 16) & 1u);   // RNE
  return (unsigned short)(u >> 16);
}
__device__ __forceinline__ float bf2f(unsigned short u) {
  return __uint_as_float(((unsigned int)u) << 16);
}
// order-preserving float<->int key (for atomicMax)
__device__ __forceinline__ int fkey(float f) {
  int b = __float_as_int(f);
  return b >= 0 ? b : (b ^ 0x7fffffff);
}
__device__ __forceinline__ float fdec(int k) {
  int b = k >= 0 ? k : (k ^ 0x7fffffff);
  return __int_as_float(b);
}

// ---------------- init: weights -> bf16 col-major; clear sums + max tables ----
__global__ void k_init(const float* __restrict__ Wmax, const float* __restrict__ Wsk,
                       unsigned char* __restrict__ ws) {
  unsigned short* wt = (unsigned short*)(ws + WT_OFF);
  float* csum = (float*)(ws + CSUM_OFF);
  float* csq  = (float*)(ws + CSQ_OFF);
  int* st = (int*)(ws + ST_OFF);
  int* gt = (int*)(ws + GT_OFF);
  int i = blockIdx.x * blockDim.x + threadIdx.x;
  const int total = NSTROKE * KDIM;   // 1048576
  for (; i < total; i += gridDim.x * blockDim.x) {
    st[i] = INT_MIN;
    if (i < NGRAPH * KDIM) gt[i] = INT_MIN;
    if (i < 256) { csum[i] = 0.f; csq[i] = 0.f; }
    if (i < 256 * KDIM) {
      int c = i / KDIM, k = i % KDIM;
      float w = (c < 128) ? Wsk[k * 128 + c] : Wmax[k * 128 + (c - 128)];
      wt[i] = f2bf(w);   // wt[c][k]
    }
  }
}

// ---------------- pass1: fused GEMM + col sums + BATCHED segment-max flush -----
// R5 change vs R2: (curseg, runmax) carried in registers across all 8 tiles;
// interior runs (exclusively owned by this block, by sortedness) flush via
// plain nontemporal store; only edge-shared runs use device-scope atomicMax.
// Cuts ~2.2M device atomics to ~0.4M.
__global__ __launch_bounds__(256) void k_pass1(const float* __restrict__ x,
                                               const int* __restrict__ batch,
                                               const int* __restrict__ stroke,
                                               unsigned char* __restrict__ ws) {
  __shared__ __align__(16) unsigned short xs[64 * 128];  // 16 KB (row-major, swz)
  __shared__ __align__(16) unsigned short hs[256 * 64];  // 32 KB (col-major, swz)
  __shared__ int ss[64];   // stroke id per tile row
  __shared__ int gg[64];   // graph id per tile row
  const unsigned short* wt = (const unsigned short*)(ws + WT_OFF);
  float* csum = (float*)(ws + CSUM_OFF);
  float* csq  = (float*)(ws + CSQ_OFF);
  int* st = (int*)(ws + ST_OFF);
  int* gt = (int*)(ws + GT_OFF);

  const int tid  = threadIdx.x;
  const int lane = tid & 63;
  const int wv   = tid >> 6;   // wave 0..3
  const int lr   = lane & 15;
  const int lg   = lane >> 4;

  // B fragments: lane holds Wt[col = wv*64+n*16+lr][k = ks*32+lg*8 ..+7]
  bf16x8 bfrag[4][4];
#pragma unroll
  for (int ks = 0; ks < 4; ++ks)
#pragma unroll
    for (int n = 0; n < 4; ++n) {
      int c = wv * 64 + n * 16 + lr;
      int k = ks * 32 + lg * 8;
      bfrag[ks][n] = *(const bf16x8*)(wt + c * KDIM + k);
    }

  float sumn[4] = {0.f, 0.f, 0.f, 0.f};
  float sqn[4]  = {0.f, 0.f, 0.f, 0.f};
  int* mp = (tid < 128) ? (st + tid) : (gt + (tid - 128));
  const int* __restrict__ segp = (tid < 128) ? stroke : batch;

  const int brow = blockIdx.x * 512;   // 8 tiles x 64 rows
  // edge segs: runs touching block edges may be shared with neighbor blocks
  const int prevedge = (brow > 0) ? segp[brow - 1] : -1;
  const int nextedge = (brow + 512 < NROWS) ? segp[brow + 512] : -2;

  int   curseg = -1;
  float runmax = -FLT_MAX;

  for (int ti = 0; ti < 8; ++ti) {
    const int row0 = brow + ti * 64;

    // ---- stage x tile (64x128 fp32 -> bf16, swizzled row-major) ----
#pragma unroll
    for (int it = 0; it < 4; ++it) {
      int e  = it * 2048 + tid * 8;
      int r  = e >> 7;
      int kg = (e & 127) >> 3;
      const float* src = x + (size_t)(row0 + r) * KDIM + kg * 8;
      f32x4 v0 = *(const f32x4*)src;
      f32x4 v1 = *(const f32x4*)(src + 4);
      union { bf16x8 v; unsigned short u[8]; } pk;
      pk.u[0] = f2bf(v0[0]); pk.u[1] = f2bf(v0[1]); pk.u[2] = f2bf(v0[2]); pk.u[3] = f2bf(v0[3]);
      pk.u[4] = f2bf(v1[0]); pk.u[5] = f2bf(v1[1]); pk.u[6] = f2bf(v1[2]); pk.u[7] = f2bf(v1[3]);
      *(bf16x8*)(xs + r * KDIM + ((kg ^ (r & 7)) << 3)) = pk.v;
    }
    if (tid < 64)       ss[tid]      = stroke[row0 + tid];
    else if (tid < 128) gg[tid - 64] = batch[row0 + tid - 64];
    __syncthreads();

    // ---- MFMA: 64 rows x 64 cols per wave ----
    f32x4 acc[4][4];
#pragma unroll
    for (int m = 0; m < 4; ++m)
#pragma unroll
      for (int n = 0; n < 4; ++n) { f32x4 z = {0.f, 0.f, 0.f, 0.f}; acc[m][n] = z; }

#pragma unroll
    for (int ks = 0; ks < 4; ++ks) {
      bf16x8 af[4];
#pragma unroll
      for (int m = 0; m < 4; ++m) {
        int r  = m * 16 + lr;
        int kg = ks * 4 + lg;
        af[m] = *(const bf16x8*)(xs + r * KDIM + ((kg ^ (r & 7)) << 3));
      }
#pragma unroll
      for (int m = 0; m < 4; ++m)
#pragma unroll
        for (int n = 0; n < 4; ++n)
          acc[m][n] = __builtin_amdgcn_mfma_f32_16x16x32_bf16(af[m], bfrag[ks][n], acc[m][n], 0, 0, 0);
    }

    // ---- column sums/sumsq straight from accumulators (f32, no LDS trip) ----
#pragma unroll
    for (int n = 0; n < 4; ++n) {
      float s = 0.f, q = 0.f;
#pragma unroll
      for (int m = 0; m < 4; ++m)
#pragma unroll
        for (int rg = 0; rg < 4; ++rg) { float v = acc[m][n][rg]; s += v; q = fmaf(v, v, q); }
      sumn[n] += s; sqn[n] += q;
    }

    // ---- dump h col-major bf16 [c][64], 16B-chunk XOR swizzle, vector b64 ----
#pragma unroll
    for (int m = 0; m < 4; ++m)
#pragma unroll
      for (int n = 0; n < 4; ++n) {
        u16x4 p;
#pragma unroll
        for (int rg = 0; rg < 4; ++rg) p[rg] = f2bf(acc[m][n][rg]);
        int c    = wv * 64 + n * 16 + lr;
        int rowb = m * 16 + lg * 4;
        int byte = (c << 7) + (((rowb >> 3) ^ (c & 7)) << 4) + ((rowb & 7) << 1);
        *(u16x4*)((char*)hs + byte) = p;
      }
    __syncthreads();

    // ---- segment scan: thread owns combined column tid; run carried across tiles ----
    const int* segl = (tid < 128) ? ss : gg;
#pragma unroll
    for (int J = 0; J < 8; ++J) {
      int byte = (tid << 7) + ((J ^ (tid & 7)) << 4);
      union { bf16x8 v; unsigned short u[8]; } hv;
      hv.v = *(const bf16x8*)((const char*)hs + byte);
#pragma unroll
      for (int rr = 0; rr < 8; ++rr) {
        float v = bf2f(hv.u[rr]);
        int seg = segl[J * 8 + rr];
        if (seg != curseg) {
          if (curseg >= 0) {
            int key = fkey(runmax);
            if (curseg == prevedge) atomicMax(&mp[curseg * KDIM], key);
            else __builtin_nontemporal_store(key, &mp[curseg * KDIM]);
          }
          curseg = seg; runmax = v;
        } else {
          runmax = fmaxf(runmax, v);
        }
      }
    }
    __syncthreads();
  }

  // ---- final run flush: shared iff it touches either block edge's segment ----
  {
    int key = fkey(runmax);
    if (curseg == nextedge || curseg == prevedge) atomicMax(&mp[curseg * KDIM], key);
    else __builtin_nontemporal_store(key, &mp[curseg * KDIM]);
  }

  // ---- finalize sums: reduce over the 4 k-group lanes, 1 atomic per column ----
#pragma unroll
  for (int n = 0; n < 4; ++n) {
    sumn[n] += __shfl_xor(sumn[n], 16);
    sumn[n] += __shfl_xor(sumn[n], 32);
    sqn[n]  += __shfl_xor(sqn[n], 16);
    sqn[n]  += __shfl_xor(sqn[n], 32);
  }
  float s = 0.f, q = 0.f;
#pragma unroll
  for (int n = 0; n < 4; ++n) if (n == lg) { s = sumn[n]; q = sqn[n]; }  // static select
  atomicAdd(&csum[tid], s);
  atomicAdd(&csq[tid], q);
}

// ---------------- out: gather + BN(affine)+ReLU on the fly + stream write ------
// (reverted to R2-exact: NT stores, unconditional pipelined gathers)
__global__ __launch_bounds__(256) void k_out(const int* __restrict__ batch,
                                             const int* __restrict__ stroke,
                                             const float* __restrict__ g_max,
                                             const float* __restrict__ be_max,
                                             const float* __restrict__ g_sk,
                                             const float* __restrict__ be_sk,
                                             const unsigned char* __restrict__ ws,
                                             float* __restrict__ out) {
  const float* csum = (const float*)(ws + CSUM_OFF);
  const float* csq  = (const float*)(ws + CSQ_OFF);
  const int* st = (const int*)(ws + ST_OFF);
  const int* gt = (const int*)(ws + GT_OFF);

  const int lane = threadIdx.x & 63;
  const int wvid = blockIdx.x * 4 + (threadIdx.x >> 6);
  const int row0 = wvid * 64;
  const bool isS = lane < 32;
  const int  cg  = (isS ? lane : lane - 32) * 4;
  const int* tab  = isS ? st : gt;
  const int* idxp = isS ? stroke : batch;
  const float* gv = isS ? g_sk : g_max;
  const float* bv = isS ? be_sk : be_max;

  const float invN = 1.0f / (float)NROWS;
  f32x4 mu, sc, bb;
#pragma unroll
  for (int j = 0; j < 4; ++j) {
    int cc = (isS ? 0 : 128) + cg + j;
    float m  = csum[cc] * invN;
    float vr = csq[cc] * invN - m * m;
    mu[j] = m;
    sc[j] = gv[cg + j] * rsqrtf(vr + EPSF);
    bb[j] = bv[cg + j];
  }

  f32x4* out4 = (f32x4*)out;
#pragma unroll 4
  for (int r = 0; r < 64; ++r) {
    int row = row0 + r;
    int seg = idxp[row];
    const int4 k4 = *(const int4*)(tab + (size_t)seg * KDIM + cg);
    f32x4 v;
    v[0] = fdec(k4.x); v[1] = fdec(k4.y); v[2] = fdec(k4.z); v[3] = fdec(k4.w);
#pragma unroll
    for (int j = 0; j < 4; ++j) v[j] = fmaxf(0.f, (v[j] - mu[j]) * sc[j] + bb[j]);
    __builtin_nontemporal_store(v, &out4[(size_t)row * 64 + lane]);
  }
}

extern "C" void kernel_launch(void* const* d_in, const int* in_sizes, int n_in,
                              void* d_out, int out_size, void* d_ws, size_t ws_size,
                              hipStream_t stream) {
  const float* x      = (const float*)d_in[0];
  const int*   batch  = (const int*)d_in[1];
  const int*   stroke = (const int*)d_in[2];
  const float* Wmax   = (const float*)d_in[3];
  const float* g_max  = (const float*)d_in[5];
  const float* be_max = (const float*)d_in[6];
  const float* Wsk    = (const float*)d_in[7];
  const float* g_sk   = (const float*)d_in[9];
  const float* be_sk  = (const float*)d_in[10];
  unsigned char* ws = (unsigned char*)d_ws;
  float* out = (float*)d_out;

  k_init <<<2048, 512, 0, stream>>>(Wmax, Wsk, ws);
  k_pass1<<<1024, 256, 0, stream>>>(x, batch, stroke, ws);
  k_out  <<<2048, 256, 0, stream>>>(batch, stroke, g_max, be_max, g_sk, be_sk, ws, out);
}

// Round 6
// 270.752 us; speedup vs baseline: 1.4035x; 1.4035x over previous
//
#include <hip/hip_runtime.h>
#include <hip/hip_bf16.h>
#include <climits>
#include <cstdint>
#include <cfloat>

#define NROWS   524288
#define KDIM    128
#define NGRAPH  64
#define NSTROKE 8192
#define EPSF    1e-5f

typedef __bf16 bf16x8 __attribute__((ext_vector_type(8)));
typedef float  f32x4  __attribute__((ext_vector_type(4)));
typedef unsigned short u16x4 __attribute__((ext_vector_type(4)));

// ws layout (bytes)
#define WT_OFF    0                         // ushort bf16 Wt[256][128] (col-major)
#define CSUM_OFF  65536                     // float[256]
#define CSQ_OFF   66560                     // float[256]
#define ST_OFF    67584                     // int [8192][128] stroke max (int-key)
#define GT_OFF    (ST_OFF + NSTROKE*KDIM*4) // int [64][128] graph max (int-key)

__device__ __forceinline__ unsigned short f2bf(float f) {
  unsigned int u = __float_as_uint(f);
  u += 0x7fffu + ((u >> 16) & 1u);   // RNE
  return (unsigned short)(u >> 16);
}
__device__ __forceinline__ float bf2f(unsigned short u) {
  return __uint_as_float(((unsigned int)u) << 16);
}
// order-preserving float<->int key (for atomicMax)
__device__ __forceinline__ int fkey(float f) {
  int b = __float_as_int(f);
  return b >= 0 ? b : (b ^ 0x7fffffff);
}
__device__ __forceinline__ float fdec(int k) {
  int b = k >= 0 ? k : (k ^ 0x7fffffff);
  return __int_as_float(b);
}

// ---------------- init: weights -> bf16 col-major; clear sums + max tables ----
__global__ void k_init(const float* __restrict__ Wmax, const float* __restrict__ Wsk,
                       unsigned char* __restrict__ ws) {
  unsigned short* wt = (unsigned short*)(ws + WT_OFF);
  float* csum = (float*)(ws + CSUM_OFF);
  float* csq  = (float*)(ws + CSQ_OFF);
  int* st = (int*)(ws + ST_OFF);
  int* gt = (int*)(ws + GT_OFF);
  int i = blockIdx.x * blockDim.x + threadIdx.x;
  const int total = NSTROKE * KDIM;   // 1048576
  for (; i < total; i += gridDim.x * blockDim.x) {
    st[i] = INT_MIN;
    if (i < NGRAPH * KDIM) gt[i] = INT_MIN;
    if (i < 256) { csum[i] = 0.f; csq[i] = 0.f; }
    if (i < 256 * KDIM) {
      int c = i / KDIM, k = i % KDIM;
      float w = (c < 128) ? Wsk[k * 128 + c] : Wmax[k * 128 + (c - 128)];
      wt[i] = f2bf(w);   // wt[c][k]
    }
  }
}

// ---------------- pass1: fused GEMM + col sums + mask-driven segment max -------
// R6 change vs R2 (flush semantics R2-exact, all atomicMax):
//   * per-tile 64-bit boundary masks built with __shfl_up + __ballot (no LDS
//     dependency chain)
//   * scan prefetches all 8 ds_read_b128 chunks into registers (pipelined),
//     then tests one uniform mask byte per chunk: 0 -> 3-deep fmax tree
//     (common case), else rare per-element walk with LDS seg read only at
//     boundaries. Removes ~512 dependent ds_read_b32 / thread.
__global__ __launch_bounds__(256) void k_pass1(const float* __restrict__ x,
                                               const int* __restrict__ batch,
                                               const int* __restrict__ stroke,
                                               unsigned char* __restrict__ ws) {
  __shared__ __align__(16) unsigned short xs[64 * 128];  // 16 KB (row-major, swz)
  __shared__ __align__(16) unsigned short hs[256 * 64];  // 32 KB (col-major, swz)
  __shared__ int ss[64];   // stroke id per tile row
  __shared__ int gg[64];   // graph id per tile row
  __shared__ unsigned long long msk[2];  // [0]=stroke boundary bits, [1]=graph
  const unsigned short* wt = (const unsigned short*)(ws + WT_OFF);
  float* csum = (float*)(ws + CSUM_OFF);
  float* csq  = (float*)(ws + CSQ_OFF);
  int* st = (int*)(ws + ST_OFF);
  int* gt = (int*)(ws + GT_OFF);

  const int tid  = threadIdx.x;
  const int lane = tid & 63;
  const int wv   = tid >> 6;   // wave 0..3
  const int lr   = lane & 15;
  const int lg   = lane >> 4;

  // B fragments: lane holds Wt[col = wv*64+n*16+lr][k = ks*32+lg*8 ..+7]
  bf16x8 bfrag[4][4];
#pragma unroll
  for (int ks = 0; ks < 4; ++ks)
#pragma unroll
    for (int n = 0; n < 4; ++n) {
      int c = wv * 64 + n * 16 + lr;
      int k = ks * 32 + lg * 8;
      bfrag[ks][n] = *(const bf16x8*)(wt + c * KDIM + k);
    }

  float sumn[4] = {0.f, 0.f, 0.f, 0.f};
  float sqn[4]  = {0.f, 0.f, 0.f, 0.f};
  int* mp = (tid < 128) ? (st + tid) : (gt + (tid - 128));

  for (int ti = 0; ti < 8; ++ti) {
    const int row0 = (blockIdx.x * 8 + ti) * 64;

    // ---- stage x tile (64x128 fp32 -> bf16, swizzled row-major) ----
#pragma unroll
    for (int it = 0; it < 4; ++it) {
      int e  = it * 2048 + tid * 8;
      int r  = e >> 7;
      int kg = (e & 127) >> 3;
      const float* src = x + (size_t)(row0 + r) * KDIM + kg * 8;
      f32x4 v0 = *(const f32x4*)src;
      f32x4 v1 = *(const f32x4*)(src + 4);
      union { bf16x8 v; unsigned short u[8]; } pk;
      pk.u[0] = f2bf(v0[0]); pk.u[1] = f2bf(v0[1]); pk.u[2] = f2bf(v0[2]); pk.u[3] = f2bf(v0[3]);
      pk.u[4] = f2bf(v1[0]); pk.u[5] = f2bf(v1[1]); pk.u[6] = f2bf(v1[2]); pk.u[7] = f2bf(v1[3]);
      *(bf16x8*)(xs + r * KDIM + ((kg ^ (r & 7)) << 3)) = pk.v;
    }
    // seg ids + boundary masks (shfl_up+ballot: no LDS dependency chain)
    if (tid < 64) {
      int sv = stroke[row0 + tid];
      ss[tid] = sv;
      int pv = __shfl_up(sv, 1);
      unsigned long long b = __ballot(tid > 0 && pv != sv);
      if (tid == 0) msk[0] = b;
    } else if (tid < 128) {
      int gv = batch[row0 + tid - 64];
      gg[tid - 64] = gv;
      int pv = __shfl_up(gv, 1);
      unsigned long long b = __ballot((tid & 63) > 0 && pv != gv);
      if (tid == 64) msk[1] = b;
    }
    __syncthreads();

    // ---- MFMA: 64 rows x 64 cols per wave ----
    f32x4 acc[4][4];
#pragma unroll
    for (int m = 0; m < 4; ++m)
#pragma unroll
      for (int n = 0; n < 4; ++n) { f32x4 z = {0.f, 0.f, 0.f, 0.f}; acc[m][n] = z; }

#pragma unroll
    for (int ks = 0; ks < 4; ++ks) {
      bf16x8 af[4];
#pragma unroll
      for (int m = 0; m < 4; ++m) {
        int r  = m * 16 + lr;
        int kg = ks * 4 + lg;
        af[m] = *(const bf16x8*)(xs + r * KDIM + ((kg ^ (r & 7)) << 3));
      }
#pragma unroll
      for (int m = 0; m < 4; ++m)
#pragma unroll
        for (int n = 0; n < 4; ++n)
          acc[m][n] = __builtin_amdgcn_mfma_f32_16x16x32_bf16(af[m], bfrag[ks][n], acc[m][n], 0, 0, 0);
    }

    // ---- column sums/sumsq straight from accumulators (f32, no LDS trip) ----
#pragma unroll
    for (int n = 0; n < 4; ++n) {
      float s = 0.f, q = 0.f;
#pragma unroll
      for (int m = 0; m < 4; ++m)
#pragma unroll
        for (int rg = 0; rg < 4; ++rg) { float v = acc[m][n][rg]; s += v; q = fmaf(v, v, q); }
      sumn[n] += s; sqn[n] += q;
    }

    // ---- dump h col-major bf16 [c][64], 16B-chunk XOR swizzle, vector b64 ----
#pragma unroll
    for (int m = 0; m < 4; ++m)
#pragma unroll
      for (int n = 0; n < 4; ++n) {
        u16x4 p;
#pragma unroll
        for (int rg = 0; rg < 4; ++rg) p[rg] = f2bf(acc[m][n][rg]);
        int c    = wv * 64 + n * 16 + lr;
        int rowb = m * 16 + lg * 4;
        int byte = (c << 7) + (((rowb >> 3) ^ (c & 7)) << 4) + ((rowb & 7) << 1);
        *(u16x4*)((char*)hs + byte) = p;
      }
    __syncthreads();

    // ---- segment max: prefetch 8 chunks, mask-byte dispatch per chunk ----
    {
      const int* segl = (tid < 128) ? ss : gg;
      const unsigned long long mask = msk[tid >> 7];
      int curseg = segl[0];
      float runmax = -FLT_MAX;

      bf16x8 hv0, hv1, hv2, hv3, hv4, hv5, hv6, hv7;
      {
        const char* hb = (const char*)hs + (tid << 7);
        hv0 = *(const bf16x8*)(hb + ((0 ^ (tid & 7)) << 4));
        hv1 = *(const bf16x8*)(hb + ((1 ^ (tid & 7)) << 4));
        hv2 = *(const bf16x8*)(hb + ((2 ^ (tid & 7)) << 4));
        hv3 = *(const bf16x8*)(hb + ((3 ^ (tid & 7)) << 4));
        hv4 = *(const bf16x8*)(hb + ((4 ^ (tid & 7)) << 4));
        hv5 = *(const bf16x8*)(hb + ((5 ^ (tid & 7)) << 4));
        hv6 = *(const bf16x8*)(hb + ((6 ^ (tid & 7)) << 4));
        hv7 = *(const bf16x8*)(hb + ((7 ^ (tid & 7)) << 4));
      }

#define SCAN_CHUNK(J, HV)                                                     \
      {                                                                       \
        union { bf16x8 v; unsigned short u[8]; } cu; cu.v = HV;               \
        unsigned mb = (unsigned)(mask >> ((J) * 8)) & 0xffu;                  \
        if (mb == 0) {                                                        \
          float a0 = fmaxf(bf2f(cu.u[0]), bf2f(cu.u[1]));                     \
          float a1 = fmaxf(bf2f(cu.u[2]), bf2f(cu.u[3]));                     \
          float a2 = fmaxf(bf2f(cu.u[4]), bf2f(cu.u[5]));                     \
          float a3 = fmaxf(bf2f(cu.u[6]), bf2f(cu.u[7]));                     \
          runmax = fmaxf(runmax, fmaxf(fmaxf(a0, a1), fmaxf(a2, a3)));        \
        } else {                                                              \
          _Pragma("unroll")                                                   \
          for (int rr = 0; rr < 8; ++rr) {                                    \
            float v = bf2f(cu.u[rr]);                                         \
            if (mb & (1u << rr)) {                                            \
              atomicMax(&mp[curseg * KDIM], fkey(runmax));                    \
              curseg = segl[(J) * 8 + rr]; runmax = v;                        \
            } else {                                                          \
              runmax = fmaxf(runmax, v);                                      \
            }                                                                 \
          }                                                                   \
        }                                                                     \
      }
      SCAN_CHUNK(0, hv0) SCAN_CHUNK(1, hv1) SCAN_CHUNK(2, hv2) SCAN_CHUNK(3, hv3)
      SCAN_CHUNK(4, hv4) SCAN_CHUNK(5, hv5) SCAN_CHUNK(6, hv6) SCAN_CHUNK(7, hv7)
#undef SCAN_CHUNK
      atomicMax(&mp[curseg * KDIM], fkey(runmax));
    }
    __syncthreads();
  }

  // ---- finalize sums: reduce over the 4 k-group lanes, 1 atomic per column ----
#pragma unroll
  for (int n = 0; n < 4; ++n) {
    sumn[n] += __shfl_xor(sumn[n], 16);
    sumn[n] += __shfl_xor(sumn[n], 32);
    sqn[n]  += __shfl_xor(sqn[n], 16);
    sqn[n]  += __shfl_xor(sqn[n], 32);
  }
  float s = 0.f, q = 0.f;
#pragma unroll
  for (int n = 0; n < 4; ++n) if (n == lg) { s = sumn[n]; q = sqn[n]; }  // static select
  atomicAdd(&csum[tid], s);
  atomicAdd(&csq[tid], q);
}

// ---------------- out: gather + BN(affine)+ReLU on the fly + stream write ------
// (R2-exact: NT stores, unconditional pipelined gathers)
__global__ __launch_bounds__(256) void k_out(const int* __restrict__ batch,
                                             const int* __restrict__ stroke,
                                             const float* __restrict__ g_max,
                                             const float* __restrict__ be_max,
                                             const float* __restrict__ g_sk,
                                             const float* __restrict__ be_sk,
                                             const unsigned char* __restrict__ ws,
                                             float* __restrict__ out) {
  const float* csum = (const float*)(ws + CSUM_OFF);
  const float* csq  = (const float*)(ws + CSQ_OFF);
  const int* st = (const int*)(ws + ST_OFF);
  const int* gt = (const int*)(ws + GT_OFF);

  const int lane = threadIdx.x & 63;
  const int wvid = blockIdx.x * 4 + (threadIdx.x >> 6);
  const int row0 = wvid * 64;
  const bool isS = lane < 32;
  const int  cg  = (isS ? lane : lane - 32) * 4;
  const int* tab  = isS ? st : gt;
  const int* idxp = isS ? stroke : batch;
  const float* gv = isS ? g_sk : g_max;
  const float* bv = isS ? be_sk : be_max;

  const float invN = 1.0f / (float)NROWS;
  f32x4 mu, sc, bb;
#pragma unroll
  for (int j = 0; j < 4; ++j) {
    int cc = (isS ? 0 : 128) + cg + j;
    float m  = csum[cc] * invN;
    float vr = csq[cc] * invN - m * m;
    mu[j] = m;
    sc[j] = gv[cg + j] * rsqrtf(vr + EPSF);
    bb[j] = bv[cg + j];
  }

  f32x4* out4 = (f32x4*)out;
#pragma unroll 4
  for (int r = 0; r < 64; ++r) {
    int row = row0 + r;
    int seg = idxp[row];
    const int4 k4 = *(const int4*)(tab + (size_t)seg * KDIM + cg);
    f32x4 v;
    v[0] = fdec(k4.x); v[1] = fdec(k4.y); v[2] = fdec(k4.z); v[3] = fdec(k4.w);
#pragma unroll
    for (int j = 0; j < 4; ++j) v[j] = fmaxf(0.f, (v[j] - mu[j]) * sc[j] + bb[j]);
    __builtin_nontemporal_store(v, &out4[(size_t)row * 64 + lane]);
  }
}

extern "C" void kernel_launch(void* const* d_in, const int* in_sizes, int n_in,
                              void* d_out, int out_size, void* d_ws, size_t ws_size,
                              hipStream_t stream) {
  const float* x      = (const float*)d_in[0];
  const int*   batch  = (const int*)d_in[1];
  const int*   stroke = (const int*)d_in[2];
  const float* Wmax   = (const float*)d_in[3];
  const float* g_max  = (const float*)d_in[5];
  const float* be_max = (const float*)d_in[6];
  const float* Wsk    = (const float*)d_in[7];
  const float* g_sk   = (const float*)d_in[9];
  const float* be_sk  = (const float*)d_in[10];
  unsigned char* ws = (unsigned char*)d_ws;
  float* out = (float*)d_out;

  k_init <<<2048, 512, 0, stream>>>(Wmax, Wsk, ws);
  k_pass1<<<1024, 256, 0, stream>>>(x, batch, stroke, ws);
  k_out  <<<2048, 256, 0, stream>>>(batch, stroke, g_max, be_max, g_sk, be_sk, ws, out);
}